// Round 16
// baseline (70.241 us; speedup 1.0000x reference)
//
#include <hip/hip_runtime.h>
#include <hip/hip_bf16.h>

#define N 8192
#define D 256
#define NF 8192.0f

typedef __bf16 bf16x8 __attribute__((ext_vector_type(8)));
typedef float f32x4 __attribute__((ext_vector_type(4)));

static __device__ __forceinline__ unsigned short f2bf(float x) {
    union { float f; unsigned int u; } c; c.f = x;
    unsigned int r = (c.u + 0x7fffu + ((c.u >> 16) & 1u)) >> 16;
    return (unsigned short)r;
}
static __device__ __forceinline__ float bf2f(unsigned short u) {
    union { float f; unsigned int u; } c; c.u = ((unsigned int)u) << 16;
    return c.f;
}

// ---------- kernel 1: norms, exact fp32 diag, A-hat bf16 (row-major),
// ----------           Bt = B-hat^T bf16 [256][8192] via LDS transpose, v += col-sums
__global__ __launch_bounds__(256) void conv_k(const float* __restrict__ o1,
                                              const float* __restrict__ o2,
                                              unsigned char* __restrict__ a_bf,
                                              unsigned char* __restrict__ bt,
                                              float* __restrict__ v,
                                              float* __restrict__ diag) {
    __shared__ unsigned short tile[32][256];   // 16 KB: [j-local][k]
    const int w = threadIdx.x >> 6, lane = threadIdx.x & 63;
    const int r0 = blockIdx.x * 32;

    #pragma unroll
    for (int t = 0; t < 8; ++t) {
        const int jloc = w * 8 + t;
        const int r = r0 + jloc;
        float4 x1 = ((const float4*)(o1 + (size_t)r * D))[lane];
        float4 x2 = ((const float4*)(o2 + (size_t)r * D))[lane];
        float s1 = x1.x*x1.x + x1.y*x1.y + x1.z*x1.z + x1.w*x1.w;
        float s2 = x2.x*x2.x + x2.y*x2.y + x2.z*x2.z + x2.w*x2.w;
        float sd = x1.x*x2.x + x1.y*x2.y + x1.z*x2.z + x1.w*x2.w;
        #pragma unroll
        for (int m = 1; m < 64; m <<= 1) {
            s1 += __shfl_xor(s1, m);
            s2 += __shfl_xor(s2, m);
            sd += __shfl_xor(sd, m);
        }
        float i1 = 1.0f / sqrtf(s1);
        float i2 = 1.0f / sqrtf(s2);
        if (lane == 0) diag[r] = sd * i1 * i2;

        // A-hat row (bf16, row-major, 512B rows)
        uint2 qa;
        qa.x = (unsigned int)f2bf(x1.x * i1) | ((unsigned int)f2bf(x1.y * i1) << 16);
        qa.y = (unsigned int)f2bf(x1.z * i1) | ((unsigned int)f2bf(x1.w * i1) << 16);
        *(uint2*)(a_bf + (size_t)r * 512 + lane * 8) = qa;

        // B-hat row -> LDS tile
        uint2 qb;
        qb.x = (unsigned int)f2bf(x2.x * i2) | ((unsigned int)f2bf(x2.y * i2) << 16);
        qb.y = (unsigned int)f2bf(x2.z * i2) | ((unsigned int)f2bf(x2.w * i2) << 16);
        *(uint2*)&tile[jloc][lane * 4] = qb;
    }
    __syncthreads();

    // transpose out: thread t = k; write Bt[k][r0..r0+31] (64B) + v partial
    const int t = threadIdx.x;
    float vs = 0.f;
    unsigned int pk[16];
    #pragma unroll
    for (int j = 0; j < 16; ++j) {
        unsigned short y0 = tile[2 * j][t];
        unsigned short y1 = tile[2 * j + 1][t];
        vs += bf2f(y0) + bf2f(y1);
        pk[j] = (unsigned int)y0 | ((unsigned int)y1 << 16);
    }
    uint4* dst = (uint4*)(bt + (size_t)t * (2 * N) + (size_t)r0 * 2);
    #pragma unroll
    for (int q = 0; q < 4; ++q) {
        uint4 u; u.x = pk[4*q]; u.y = pk[4*q+1]; u.z = pk[4*q+2]; u.w = pk[4*q+3];
        dst[q] = u;
    }
    atomicAdd(v + t, vs);
}

// ---------- kernel 2: M partials. M = Bt x Bt^T (over j-window of 256).
// grid 32; block 512 = 8 waves (2m x 4n), wave-tile 128x64 of the 256x256 output.
__global__ __launch_bounds__(512) void mker(const unsigned char* __restrict__ bt,
                                            float* __restrict__ pM) {
    const int tid = threadIdx.x, lane = tid & 63, wid = tid >> 6;
    const int wm = wid & 1, wn = wid >> 1;
    const int l15 = lane & 15, lk = lane >> 4;
    const int j0 = blockIdx.x * 256;

    f32x4 acc[8][4];
    #pragma unroll
    for (int mt = 0; mt < 8; ++mt)
        #pragma unroll
        for (int nt = 0; nt < 4; ++nt)
            acc[mt][nt] = (f32x4){0.f, 0.f, 0.f, 0.f};

    #pragma unroll
    for (int ks = 0; ks < 8; ++ks) {
        const size_t joff = (size_t)(j0 + ks * 32) * 2 + lk * 16;
        bf16x8 afr[8], bfr[4];
        #pragma unroll
        for (int mt = 0; mt < 8; ++mt)
            afr[mt] = *(const bf16x8*)(bt + (size_t)(wm * 128 + mt * 16 + l15) * (2 * N) + joff);
        #pragma unroll
        for (int nt = 0; nt < 4; ++nt)
            bfr[nt] = *(const bf16x8*)(bt + (size_t)(wn * 64 + nt * 16 + l15) * (2 * N) + joff);
        #pragma unroll
        for (int mt = 0; mt < 8; ++mt)
            #pragma unroll
            for (int nt = 0; nt < 4; ++nt)
                acc[mt][nt] = __builtin_amdgcn_mfma_f32_16x16x32_bf16(
                    afr[mt], bfr[nt], acc[mt][nt], 0, 0, 0);
    }

    float* out = pM + (size_t)blockIdx.x * (D * D);
    #pragma unroll
    for (int mt = 0; mt < 8; ++mt)
        #pragma unroll
        for (int nt = 0; nt < 4; ++nt)
            #pragma unroll
            for (int rg = 0; rg < 4; ++rg) {
                int row = wm * 128 + mt * 16 + lk * 4 + rg;
                int col = wn * 64 + nt * 16 + l15;
                out[row * D + col] = acc[mt][nt][rg];
            }
}

// ---------- kernel 3: reduce 32 partials -> Mb (bf16 [256][256]) ----------
__global__ __launch_bounds__(512) void redcvt(const float* __restrict__ pM,
                                              unsigned short* __restrict__ Mb) {
    const int i = blockIdx.x * 512 + threadIdx.x;   // 0..65535
    float s = 0.f;
    #pragma unroll
    for (int b = 0; b < 32; ++b) s += pM[(size_t)b * (D * D) + i];
    Mb[i] = f2bf(s);
}

// ---------- kernel 4: quadratic forms. Y = A-hat x M (B-frags = Mb rows by symmetry);
// S2_i = <Y_i, a-hat_i>, S1_i = <a-hat_i, v> on the n-slice; partials to s1p/s2p.
// grid 512 = 64 row-groups x 8 col-eighths; block 256 = 4 waves x 32 rows.
__global__ __launch_bounds__(256) void qf_k(const unsigned char* __restrict__ a_bf,
                                            const unsigned char* __restrict__ Mb,
                                            const float* __restrict__ v,
                                            float* __restrict__ s1p,
                                            float* __restrict__ s2p) {
    const int tid = threadIdx.x, lane = tid & 63, wid = tid >> 6;
    const int l15 = lane & 15, lk = lane >> 4;
    const int rq = blockIdx.x >> 3, ne = blockIdx.x & 7;
    const int rowbase = rq * 128 + wid * 32;

    bf16x8 af[2][8];
    #pragma unroll
    for (int mr = 0; mr < 2; ++mr)
        #pragma unroll
        for (int ks = 0; ks < 8; ++ks)
            af[mr][ks] = *(const bf16x8*)(a_bf + (size_t)(rowbase + mr * 16 + l15) * 512
                                               + ks * 64 + lk * 16);

    f32x4 acc[2][2];
    #pragma unroll
    for (int mr = 0; mr < 2; ++mr)
        #pragma unroll
        for (int nt = 0; nt < 2; ++nt)
            acc[mr][nt] = (f32x4){0.f, 0.f, 0.f, 0.f};

    #pragma unroll
    for (int ks = 0; ks < 8; ++ks) {
        bf16x8 bfr[2];
        #pragma unroll
        for (int nt = 0; nt < 2; ++nt) {
            int n = ne * 32 + nt * 16 + l15;
            // B[k][n] = M[k][n] = M[n][k]  (symmetric) -> row n of Mb, k-contiguous
            bfr[nt] = *(const bf16x8*)(Mb + (size_t)n * 512 + ks * 64 + lk * 16);
        }
        #pragma unroll
        for (int mr = 0; mr < 2; ++mr)
            #pragma unroll
            for (int nt = 0; nt < 2; ++nt)
                acc[mr][nt] = __builtin_amdgcn_mfma_f32_16x16x32_bf16(
                    af[mr][ks], bfr[nt], acc[mr][nt], 0, 0, 0);
    }

    // epilogue: C layout col = l15(+16nt), row = lk*4+rg (+16mr)
    #pragma unroll
    for (int mr = 0; mr < 2; ++mr)
        #pragma unroll
        for (int rg = 0; rg < 4; ++rg) {
            const int row = rowbase + mr * 16 + lk * 4 + rg;
            const int c0 = ne * 32 + l15;
            const int c1 = ne * 32 + 16 + l15;
            float a0 = bf2f(*(const unsigned short*)(a_bf + (size_t)row * 512 + c0 * 2));
            float a1 = bf2f(*(const unsigned short*)(a_bf + (size_t)row * 512 + c1 * 2));
            float s2v = acc[mr][0][rg] * a0 + acc[mr][1][rg] * a1;
            float s1v = a0 * v[c0] + a1 * v[c1];
            #pragma unroll
            for (int m = 1; m < 16; m <<= 1) {
                s2v += __shfl_xor(s2v, m);
                s1v += __shfl_xor(s1v, m);
            }
            if (l15 == 0) {
                s2p[(size_t)ne * N + row] = s2v;
                s1p[(size_t)ne * N + row] = s1v;
            }
        }
}

// ---------- kernel 5: per-row loss = log(N + S1 + S2/2) - diag ----------
__global__ __launch_bounds__(128) void rowloss5(const float* __restrict__ s1p,
                                                const float* __restrict__ s2p,
                                                const float* __restrict__ diag,
                                                float* __restrict__ partial) {
    const int t = threadIdx.x, b = blockIdx.x;
    const int row = b * 128 + t;
    float s1 = 0.f, s2 = 0.f;
    #pragma unroll
    for (int ne = 0; ne < 8; ++ne) {
        s1 += s1p[(size_t)ne * N + row];
        s2 += s2p[(size_t)ne * N + row];
    }
    float z = NF + s1 + 0.5f * s2;
    float loss = logf(z) - diag[row];
    #pragma unroll
    for (int m = 1; m < 64; m <<= 1) loss += __shfl_xor(loss, m);
    __shared__ float redl[2];
    if ((t & 63) == 0) redl[t >> 6] = loss;
    __syncthreads();
    if (t == 0) partial[b] = redl[0] + redl[1];
}

// ---------- kernel 6: final mean ----------
__global__ __launch_bounds__(64) void final_k(const float* __restrict__ partial,
                                              float* __restrict__ out) {
    const int t = threadIdx.x;
    float x = partial[t];
    #pragma unroll
    for (int m = 1; m < 64; m <<= 1) x += __shfl_xor(x, m);
    if (t == 0) out[0] = x / NF;
}

extern "C" void kernel_launch(void* const* d_in, const int* in_sizes, int n_in,
                              void* d_out, int out_size, void* d_ws, size_t ws_size,
                              hipStream_t stream) {
    const float* o1 = (const float*)d_in[0];
    const float* o2 = (const float*)d_in[1];

    unsigned char* w = (unsigned char*)d_ws;
    unsigned char*  a_bf = w;                                   // 4 MB
    unsigned char*  bt   = w + (size_t) 4 * 1024 * 1024;        // 4 MB
    float*          pM   = (float*)(w + (size_t) 8 * 1024 * 1024);   // 8 MB
    unsigned short* Mb   = (unsigned short*)(w + (size_t)16 * 1024 * 1024); // 128 KB
    float*          v    = (float*)(w + (size_t)16 * 1024 * 1024 + 131072); // 1 KB
    float*          diag = v + 1024;                            // 32 KB
    float*          s1p  = diag + N;                            // 256 KB
    float*          s2p  = s1p + (size_t)8 * N;                 // 256 KB
    float*          partial = s2p + (size_t)8 * N;              // 256 B

    hipMemsetAsync(v, 0, D * sizeof(float), stream);
    conv_k <<<N / 32, 256, 0, stream>>>(o1, o2, a_bf, bt, v, diag);
    mker   <<<32, 512, 0, stream>>>(bt, pM);
    redcvt <<<(D * D) / 512, 512, 0, stream>>>(pM, Mb);
    qf_k   <<<512, 256, 0, stream>>>(a_bf, (const unsigned char*)Mb, v, s1p, s2p);
    rowloss5<<<N / 128, 128, 0, stream>>>(s1p, s2p, diag, partial);
    final_k<<<1, 64, 0, stream>>>(partial, (float*)d_out);
}

// Round 17
// 61.438 us; speedup vs baseline: 1.1433x; 1.1433x over previous
//
#include <hip/hip_runtime.h>
#include <hip/hip_bf16.h>

#define N 8192
#define D 256
#define NF 8192.0f

typedef __bf16 bf16x8 __attribute__((ext_vector_type(8)));
typedef float f32x4 __attribute__((ext_vector_type(4)));

static __device__ __forceinline__ unsigned short f2bf(float x) {
    union { float f; unsigned int u; } c; c.f = x;
    unsigned int r = (c.u + 0x7fffu + ((c.u >> 16) & 1u)) >> 16;
    return (unsigned short)r;
}
static __device__ __forceinline__ float bf2f(unsigned short u) {
    union { float f; unsigned int u; } c; c.u = ((unsigned int)u) << 16;
    return c.f;
}

// ---------- kernel 1: norms, exact fp32 diag, A-hat bf16 (row-major),
// ----------           Bt = B-hat^T bf16 [256][8192] via LDS transpose ----------
__global__ __launch_bounds__(256) void conv_k(const float* __restrict__ o1,
                                              const float* __restrict__ o2,
                                              unsigned char* __restrict__ a_bf,
                                              unsigned char* __restrict__ bt,
                                              float* __restrict__ diag) {
    __shared__ unsigned short tile[32][256];   // 16 KB: [j-local][k]
    const int w = threadIdx.x >> 6, lane = threadIdx.x & 63;
    const int r0 = blockIdx.x * 32;

    #pragma unroll
    for (int t = 0; t < 8; ++t) {
        const int jloc = w * 8 + t;
        const int r = r0 + jloc;
        float4 x1 = ((const float4*)(o1 + (size_t)r * D))[lane];
        float4 x2 = ((const float4*)(o2 + (size_t)r * D))[lane];
        float s1 = x1.x*x1.x + x1.y*x1.y + x1.z*x1.z + x1.w*x1.w;
        float s2 = x2.x*x2.x + x2.y*x2.y + x2.z*x2.z + x2.w*x2.w;
        float sd = x1.x*x2.x + x1.y*x2.y + x1.z*x2.z + x1.w*x2.w;
        #pragma unroll
        for (int m = 1; m < 64; m <<= 1) {
            s1 += __shfl_xor(s1, m);
            s2 += __shfl_xor(s2, m);
            sd += __shfl_xor(sd, m);
        }
        float i1 = 1.0f / sqrtf(s1);
        float i2 = 1.0f / sqrtf(s2);
        if (lane == 0) diag[r] = sd * i1 * i2;

        // A-hat row (bf16, row-major, 512B rows)
        uint2 qa;
        qa.x = (unsigned int)f2bf(x1.x * i1) | ((unsigned int)f2bf(x1.y * i1) << 16);
        qa.y = (unsigned int)f2bf(x1.z * i1) | ((unsigned int)f2bf(x1.w * i1) << 16);
        *(uint2*)(a_bf + (size_t)r * 512 + lane * 8) = qa;

        // B-hat row -> LDS tile
        uint2 qb;
        qb.x = (unsigned int)f2bf(x2.x * i2) | ((unsigned int)f2bf(x2.y * i2) << 16);
        qb.y = (unsigned int)f2bf(x2.z * i2) | ((unsigned int)f2bf(x2.w * i2) << 16);
        *(uint2*)&tile[jloc][lane * 4] = qb;
    }
    __syncthreads();

    // transpose out: thread t = k; write Bt[k][r0..r0+31] (64B)
    const int t = threadIdx.x;
    unsigned int pk[16];
    #pragma unroll
    for (int j = 0; j < 16; ++j) {
        unsigned short y0 = tile[2 * j][t];
        unsigned short y1 = tile[2 * j + 1][t];
        pk[j] = (unsigned int)y0 | ((unsigned int)y1 << 16);
    }
    uint4* dst = (uint4*)(bt + (size_t)t * (2 * N) + (size_t)r0 * 2);
    #pragma unroll
    for (int q = 0; q < 4; ++q) {
        uint4 u; u.x = pk[4*q]; u.y = pk[4*q+1]; u.z = pk[4*q+2]; u.w = pk[4*q+3];
        dst[q] = u;
    }
}

// ---------- kernel 2: M partials. M = Bt x Bt^T (over j-window of 256).
// grid 32; block 512 = 8 waves (2m x 4n), wave-tile 128x64 of the 256x256 output.
__global__ __launch_bounds__(512) void mker(const unsigned char* __restrict__ bt,
                                            float* __restrict__ pM) {
    const int tid = threadIdx.x, lane = tid & 63, wid = tid >> 6;
    const int wm = wid & 1, wn = wid >> 1;
    const int l15 = lane & 15, lk = lane >> 4;
    const int j0 = blockIdx.x * 256;

    f32x4 acc[8][4];
    #pragma unroll
    for (int mt = 0; mt < 8; ++mt)
        #pragma unroll
        for (int nt = 0; nt < 4; ++nt)
            acc[mt][nt] = (f32x4){0.f, 0.f, 0.f, 0.f};

    #pragma unroll
    for (int ks = 0; ks < 8; ++ks) {
        const size_t joff = (size_t)(j0 + ks * 32) * 2 + lk * 16;
        bf16x8 afr[8], bfr[4];
        #pragma unroll
        for (int mt = 0; mt < 8; ++mt)
            afr[mt] = *(const bf16x8*)(bt + (size_t)(wm * 128 + mt * 16 + l15) * (2 * N) + joff);
        #pragma unroll
        for (int nt = 0; nt < 4; ++nt)
            bfr[nt] = *(const bf16x8*)(bt + (size_t)(wn * 64 + nt * 16 + l15) * (2 * N) + joff);
        #pragma unroll
        for (int mt = 0; mt < 8; ++mt)
            #pragma unroll
            for (int nt = 0; nt < 4; ++nt)
                acc[mt][nt] = __builtin_amdgcn_mfma_f32_16x16x32_bf16(
                    afr[mt], bfr[nt], acc[mt][nt], 0, 0, 0);
    }

    float* out = pM + (size_t)blockIdx.x * (D * D);
    #pragma unroll
    for (int mt = 0; mt < 8; ++mt)
        #pragma unroll
        for (int nt = 0; nt < 4; ++nt)
            #pragma unroll
            for (int rg = 0; rg < 4; ++rg) {
                int row = wm * 128 + mt * 16 + lk * 4 + rg;
                int col = wn * 64 + nt * 16 + l15;
                out[row * D + col] = acc[mt][nt][rg];
            }
}

// ---------- kernel 3: reduce 32 partials -> Mb (bf16) AND v = Bt row-sums ----------
// grid 128 x 512 threads. Mb: thread i sums 32 partials. v: threads 0-255 sum
// Bt row 2b, threads 256-511 row 2b+1 (wave-reduce, LDS combine, fp32 out).
__global__ __launch_bounds__(512) void redcvt(const float* __restrict__ pM,
                                              const unsigned char* __restrict__ bt,
                                              unsigned short* __restrict__ Mb,
                                              float* __restrict__ v) {
    const int i = blockIdx.x * 512 + threadIdx.x;   // 0..65535
    float s = 0.f;
    #pragma unroll
    for (int b = 0; b < 32; ++b) s += pM[(size_t)b * (D * D) + i];
    Mb[i] = f2bf(s);

    // v: row = 2*blockIdx + (tid>=256); each thread sums 32 contiguous bf16 (64 B)
    const int lane = threadIdx.x & 63, wid = threadIdx.x >> 6;
    const int half = threadIdx.x >> 8;              // 0 or 1
    const int t255 = threadIdx.x & 255;
    const int row = blockIdx.x * 2 + half;
    const uint4* sp = (const uint4*)(bt + (size_t)row * (2 * N) + t255 * 64);
    float vs = 0.f;
    #pragma unroll
    for (int q = 0; q < 4; ++q) {
        uint4 u = sp[q];
        unsigned int ww[4] = {u.x, u.y, u.z, u.w};
        #pragma unroll
        for (int e = 0; e < 4; ++e) {
            vs += bf2f((unsigned short)(ww[e] & 0xffffu));
            vs += bf2f((unsigned short)(ww[e] >> 16));
        }
    }
    #pragma unroll
    for (int m = 1; m < 64; m <<= 1) vs += __shfl_xor(vs, m);
    __shared__ float vred[8];
    if (lane == 0) vred[wid] = vs;
    __syncthreads();
    if (threadIdx.x == 0)   v[row]     = vred[0] + vred[1] + vred[2] + vred[3];
    if (threadIdx.x == 256) v[row]     = vred[4] + vred[5] + vred[6] + vred[7];
}

// ---------- kernel 4: quadratic forms. Y = A-hat x M (B-frags = Mb rows by symmetry);
// S2_i = <Y_i, a-hat_i>, S1_i = <a-hat_i, v> on the n-slice; partials to s1p/s2p.
// grid 512 = 64 row-groups x 8 col-eighths; block 256 = 4 waves x 32 rows.
__global__ __launch_bounds__(256) void qf_k(const unsigned char* __restrict__ a_bf,
                                            const unsigned char* __restrict__ Mb,
                                            const float* __restrict__ v,
                                            float* __restrict__ s1p,
                                            float* __restrict__ s2p) {
    const int tid = threadIdx.x, lane = tid & 63, wid = tid >> 6;
    const int l15 = lane & 15, lk = lane >> 4;
    const int rq = blockIdx.x >> 3, ne = blockIdx.x & 7;
    const int rowbase = rq * 128 + wid * 32;

    bf16x8 af[2][8];
    #pragma unroll
    for (int mr = 0; mr < 2; ++mr)
        #pragma unroll
        for (int ks = 0; ks < 8; ++ks)
            af[mr][ks] = *(const bf16x8*)(a_bf + (size_t)(rowbase + mr * 16 + l15) * 512
                                               + ks * 64 + lk * 16);

    f32x4 acc[2][2];
    #pragma unroll
    for (int mr = 0; mr < 2; ++mr)
        #pragma unroll
        for (int nt = 0; nt < 2; ++nt)
            acc[mr][nt] = (f32x4){0.f, 0.f, 0.f, 0.f};

    #pragma unroll
    for (int ks = 0; ks < 8; ++ks) {
        bf16x8 bfr[2];
        #pragma unroll
        for (int nt = 0; nt < 2; ++nt) {
            int n = ne * 32 + nt * 16 + l15;
            // B[k][n] = M[k][n] = M[n][k]  (symmetric) -> row n of Mb, k-contiguous
            bfr[nt] = *(const bf16x8*)(Mb + (size_t)n * 512 + ks * 64 + lk * 16);
        }
        #pragma unroll
        for (int mr = 0; mr < 2; ++mr)
            #pragma unroll
            for (int nt = 0; nt < 2; ++nt)
                acc[mr][nt] = __builtin_amdgcn_mfma_f32_16x16x32_bf16(
                    af[mr][ks], bfr[nt], acc[mr][nt], 0, 0, 0);
    }

    // epilogue: C layout col = l15(+16nt), row = lk*4+rg (+16mr)
    #pragma unroll
    for (int mr = 0; mr < 2; ++mr)
        #pragma unroll
        for (int rg = 0; rg < 4; ++rg) {
            const int row = rowbase + mr * 16 + lk * 4 + rg;
            const int c0 = ne * 32 + l15;
            const int c1 = ne * 32 + 16 + l15;
            float a0 = bf2f(*(const unsigned short*)(a_bf + (size_t)row * 512 + c0 * 2));
            float a1 = bf2f(*(const unsigned short*)(a_bf + (size_t)row * 512 + c1 * 2));
            float s2v = acc[mr][0][rg] * a0 + acc[mr][1][rg] * a1;
            float s1v = a0 * v[c0] + a1 * v[c1];
            #pragma unroll
            for (int m = 1; m < 16; m <<= 1) {
                s2v += __shfl_xor(s2v, m);
                s1v += __shfl_xor(s1v, m);
            }
            if (l15 == 0) {
                s2p[(size_t)ne * N + row] = s2v;
                s1p[(size_t)ne * N + row] = s1v;
            }
        }
}

// ---------- kernel 5: per-row loss = log(N + S1 + S2/2) - diag ----------
__global__ __launch_bounds__(128) void rowloss5(const float* __restrict__ s1p,
                                                const float* __restrict__ s2p,
                                                const float* __restrict__ diag,
                                                float* __restrict__ partial) {
    const int t = threadIdx.x, b = blockIdx.x;
    const int row = b * 128 + t;
    float s1 = 0.f, s2 = 0.f;
    #pragma unroll
    for (int ne = 0; ne < 8; ++ne) {
        s1 += s1p[(size_t)ne * N + row];
        s2 += s2p[(size_t)ne * N + row];
    }
    float z = NF + s1 + 0.5f * s2;
    float loss = logf(z) - diag[row];
    #pragma unroll
    for (int m = 1; m < 64; m <<= 1) loss += __shfl_xor(loss, m);
    __shared__ float redl[2];
    if ((t & 63) == 0) redl[t >> 6] = loss;
    __syncthreads();
    if (t == 0) partial[b] = redl[0] + redl[1];
}

// ---------- kernel 6: final mean ----------
__global__ __launch_bounds__(64) void final_k(const float* __restrict__ partial,
                                              float* __restrict__ out) {
    const int t = threadIdx.x;
    float x = partial[t];
    #pragma unroll
    for (int m = 1; m < 64; m <<= 1) x += __shfl_xor(x, m);
    if (t == 0) out[0] = x / NF;
}

extern "C" void kernel_launch(void* const* d_in, const int* in_sizes, int n_in,
                              void* d_out, int out_size, void* d_ws, size_t ws_size,
                              hipStream_t stream) {
    const float* o1 = (const float*)d_in[0];
    const float* o2 = (const float*)d_in[1];

    unsigned char* w = (unsigned char*)d_ws;
    unsigned char*  a_bf = w;                                   // 4 MB
    unsigned char*  bt   = w + (size_t) 4 * 1024 * 1024;        // 4 MB
    float*          pM   = (float*)(w + (size_t) 8 * 1024 * 1024);   // 8 MB
    unsigned short* Mb   = (unsigned short*)(w + (size_t)16 * 1024 * 1024); // 128 KB
    float*          v    = (float*)(w + (size_t)16 * 1024 * 1024 + 131072); // 1 KB
    float*          diag = v + 1024;                            // 32 KB
    float*          s1p  = diag + N;                            // 256 KB
    float*          s2p  = s1p + (size_t)8 * N;                 // 256 KB
    float*          partial = s2p + (size_t)8 * N;              // 256 B

    conv_k <<<N / 32, 256, 0, stream>>>(o1, o2, a_bf, bt, diag);
    mker   <<<32, 512, 0, stream>>>(bt, pM);
    redcvt <<<(D * D) / 512, 512, 0, stream>>>(pM, bt, Mb, v);
    qf_k   <<<512, 256, 0, stream>>>(a_bf, (const unsigned char*)Mb, v, s1p, s2p);
    rowloss5<<<N / 128, 128, 0, stream>>>(s1p, s2p, diag, partial);
    final_k<<<1, 64, 0, stream>>>(partial, (float*)d_out);
}